// Round 1
// 571.096 us; speedup vs baseline: 1.0467x; 1.0467x over previous
//
#include <hip/hip_runtime.h>
#include <math.h>

#define ROWS 65536
#define DIM  256
#define KC   1024
#define NQ   (ROWS * DIM)

// ---- ws layout (bytes) ----
// [0]      double lossacc
// [16]     int    counts[1024]        (ends 4112)
// [4224]   float  B32[1024]           (ends 8320)
// [270464] int    idx32[65536]

// ---------------------------------------------------------------------------
// numpy pairwise sum-of-squares helpers (identical op order to the original
// sq_sum_numpy: two 128-halves, 8 accumulators each, tree combine, halves
// added last; __fmul_rn/__fadd_rn forbid fma contraction).
// ---------------------------------------------------------------------------
__device__ __forceinline__ float half_sq_sum(const float* __restrict__ a) {
    float4 u0 = *(const float4*)(a);
    float4 u1 = *(const float4*)(a + 4);
    float r0 = __fmul_rn(u0.x, u0.x);
    float r1 = __fmul_rn(u0.y, u0.y);
    float r2 = __fmul_rn(u0.z, u0.z);
    float r3 = __fmul_rn(u0.w, u0.w);
    float r4 = __fmul_rn(u1.x, u1.x);
    float r5 = __fmul_rn(u1.y, u1.y);
    float r6 = __fmul_rn(u1.z, u1.z);
    float r7 = __fmul_rn(u1.w, u1.w);
    for (int i = 8; i < 128; i += 8) {
        float4 v0 = *(const float4*)(a + i);
        float4 v1 = *(const float4*)(a + i + 4);
        r0 = __fadd_rn(r0, __fmul_rn(v0.x, v0.x));
        r1 = __fadd_rn(r1, __fmul_rn(v0.y, v0.y));
        r2 = __fadd_rn(r2, __fmul_rn(v0.z, v0.z));
        r3 = __fadd_rn(r3, __fmul_rn(v0.w, v0.w));
        r4 = __fadd_rn(r4, __fmul_rn(v1.x, v1.x));
        r5 = __fadd_rn(r5, __fmul_rn(v1.y, v1.y));
        r6 = __fadd_rn(r6, __fmul_rn(v1.z, v1.z));
        r7 = __fadd_rn(r7, __fmul_rn(v1.w, v1.w));
    }
    float s01 = __fadd_rn(r0, r1);
    float s23 = __fadd_rn(r2, r3);
    float s45 = __fadd_rn(r4, r5);
    float s67 = __fadd_rn(r6, r7);
    return __fadd_rn(__fadd_rn(s01, s23), __fadd_rn(s45, s67));
}

__device__ __forceinline__ float sq_sum_numpy(const float* __restrict__ p) {
    float h0 = half_sq_sum(p);
    float h1 = half_sq_sum(p + 128);
    return __fadd_rn(h0, h1);
}

// ---------------- K0: codebook squared norms (fp32, numpy order) -----------
__global__ __launch_bounds__(256) void k_prepB(const float* __restrict__ E,
                                               float* __restrict__ B32) {
    int j = blockIdx.x * 256 + threadIdx.x;
    if (j >= KC) return;
    B32[j] = sq_sum_numpy(E + (size_t)j * DIM);
}

// ---------------- K1: fp32 dist + first-index argmin -----------------------
// block = 256 threads; tile 128 rows x 128 cols; D staged in chunks of 32.
// LDS: double-buffered, XOR-swizzled float4 chunks (chunk ^= (d>>2)&7 inside
// each unpadded 128-float row) -> conflict-free ds_read_b128 AND ds_write.
// Staging is reg-staged issue-early / write-late (one barrier per staging).
// acc[i][j] is a single fp32 fma chain over d = 0..255 ascending from 0 --
// bit-identical to the previous passing kernel.  Row norms (numpy halves)
// are computed in-block (fused k_prepA).
#define TM 128
#define TN 128
#define TD 32
#define BUFF 4096      // floats per staged array  (TD*128)
#define BSTR 8192      // floats per buffer slot   (Xs+Es)

__global__ __launch_bounds__(256, 2) void k_pass1(
    const float* __restrict__ X, const float* __restrict__ E,
    const float* __restrict__ B32, int* __restrict__ idx32)
{
    __shared__ __align__(16) float sm[2 * BSTR];   // 65536 B -> 2 blocks/CU

    const int tid = threadIdx.x;
    const int tx  = tid & 15;        // col group: cols {tx*4..+3, 64+tx*4..+3}
    const int ty  = tid >> 4;        // row group (8 rows each)
    const int rowbase = blockIdx.x * TM;

    float4 xv0, xv1, xv2, xv3, ev0, ev1, ev2, ev3;

#define LOADR(cbn, dcn)                                                         \
    do {                                                                        \
        int fi_, r_, d4_;                                                       \
        fi_ = tid;       r_ = fi_ >> 3; d4_ = (fi_ & 7) << 2;                   \
        xv0 = *(const float4*)(X + (size_t)(rowbase + r_) * DIM + (dcn) + d4_); \
        ev0 = *(const float4*)(E + (size_t)((cbn) + r_) * DIM + (dcn) + d4_);   \
        fi_ = tid + 256; r_ = fi_ >> 3; d4_ = (fi_ & 7) << 2;                   \
        xv1 = *(const float4*)(X + (size_t)(rowbase + r_) * DIM + (dcn) + d4_); \
        ev1 = *(const float4*)(E + (size_t)((cbn) + r_) * DIM + (dcn) + d4_);   \
        fi_ = tid + 512; r_ = fi_ >> 3; d4_ = (fi_ & 7) << 2;                   \
        xv2 = *(const float4*)(X + (size_t)(rowbase + r_) * DIM + (dcn) + d4_); \
        ev2 = *(const float4*)(E + (size_t)((cbn) + r_) * DIM + (dcn) + d4_);   \
        fi_ = tid + 768; r_ = fi_ >> 3; d4_ = (fi_ & 7) << 2;                   \
        xv3 = *(const float4*)(X + (size_t)(rowbase + r_) * DIM + (dcn) + d4_); \
        ev3 = *(const float4*)(E + (size_t)((cbn) + r_) * DIM + (dcn) + d4_);   \
    } while (0)

// element (row d4+j, col r) -> offset (d4+j)*128 + (((r>>2) ^ (d4>>2))<<2) + (r&3)
#define WRITE1(Xs_, Es_, v_, e_, fif_)                                          \
    do {                                                                        \
        int r_ = (fif_) >> 3, d4_ = ((fif_) & 7) << 2;                          \
        int off_ = d4_ * 128 + ((((r_) >> 2) ^ (d4_ >> 2)) << 2) + ((r_) & 3);  \
        (Xs_)[off_]       = v_.x; (Xs_)[off_ + 128] = v_.y;                     \
        (Xs_)[off_ + 256] = v_.z; (Xs_)[off_ + 384] = v_.w;                     \
        (Es_)[off_]       = e_.x; (Es_)[off_ + 128] = e_.y;                     \
        (Es_)[off_ + 256] = e_.z; (Es_)[off_ + 384] = e_.w;                     \
    } while (0)

#define WRITEB(b)                                                               \
    do {                                                                        \
        float* Xs_ = sm + (b) * BSTR;                                           \
        float* Es_ = Xs_ + BUFF;                                                \
        WRITE1(Xs_, Es_, xv0, ev0, tid);                                        \
        WRITE1(Xs_, Es_, xv1, ev1, tid + 256);                                  \
        WRITE1(Xs_, Es_, xv2, ev2, tid + 512);                                  \
        WRITE1(Xs_, Es_, xv3, ev3, tid + 768);                                  \
    } while (0)

    // ---- prologue: issue first staging loads early ----
    LOADR(0, 0);

    // ---- fused row-norm prep (2 threads per row, numpy halves) ----
    {
        int r = tid >> 1, h = tid & 1;
        sm[(r << 1) + h] = half_sq_sum(X + (size_t)(rowbase + r) * DIM + (h << 7));
    }
    __syncthreads();
    float a8[8];
#pragma unroll
    for (int i = 0; i < 8; ++i)
        a8[i] = __fadd_rn(sm[(ty * 8 + i) * 2], sm[(ty * 8 + i) * 2 + 1]);
    __syncthreads();
    WRITEB(0);

    float v1[8]; int i1[8];
#pragma unroll
    for (int i = 0; i < 8; ++i) { v1[i] = 3.0e38f; i1[i] = 0; }

    int cur = 0;
    for (int cb8 = 0; cb8 < 8; ++cb8) {
        const int cbase = cb8 * TN;
        float4 bq0 = *(const float4*)(B32 + cbase + (tx << 2));
        float4 bq1 = *(const float4*)(B32 + cbase + 64 + (tx << 2));

        float acc[8][8];
#pragma unroll
        for (int i = 0; i < 8; ++i)
#pragma unroll
            for (int j = 0; j < 8; ++j) acc[i][j] = 0.0f;

        for (int dc8 = 0; dc8 < 8; ++dc8) {
            const int s = cb8 * 8 + dc8;
            __syncthreads();                 // buf[cur] staged & safe to reuse other buf
            if (s < 63) {
                const int sn = s + 1;
                LOADR((sn >> 3) * TN, (sn & 7) * TD);
            }
            {
                const float* Xc = sm + cur * BSTR;
                const float* Ec = Xc + BUFF;
#pragma unroll 2
                for (int dq = 0; dq < 8; ++dq) {
                    const float* xp0 = Xc + dq * 512 + ((((ty << 1)    ) ^ dq) << 2);
                    const float* xp1 = Xc + dq * 512 + ((((ty << 1) | 1) ^ dq) << 2);
                    const float* ep0 = Ec + dq * 512 + ((tx ^ dq) << 2);
#pragma unroll
                    for (int ddi = 0; ddi < 4; ++ddi) {
                        float4 t0 = *(const float4*)(xp0 + ddi * 128);
                        float4 t1 = *(const float4*)(xp1 + ddi * 128);
                        float4 u0 = *(const float4*)(ep0 + ddi * 128);
                        float4 u1 = *(const float4*)(ep0 + ddi * 128 + 64);
                        float xr[8] = {t0.x, t0.y, t0.z, t0.w, t1.x, t1.y, t1.z, t1.w};
                        float er[8] = {u0.x, u0.y, u0.z, u0.w, u1.x, u1.y, u1.z, u1.w};
#pragma unroll
                        for (int i = 0; i < 8; ++i)
#pragma unroll
                            for (int j = 0; j < 8; ++j)
                                acc[i][j] = fmaf(xr[i], er[j], acc[i][j]);
                    }
                }
            }
            if (s < 63) WRITEB(cur ^ 1);     // write-late: lands in the other buffer
            cur ^= 1;
        }

        // fold this col-block: dist = fl(fl(A + B) - 2*dot), numpy rounding.
        float bvv[8] = {bq0.x, bq0.y, bq0.z, bq0.w, bq1.x, bq1.y, bq1.z, bq1.w};
#pragma unroll
        for (int j = 0; j < 8; ++j) {
            const int c = cbase + ((j < 4) ? ((tx << 2) + j)
                                           : (64 + (tx << 2) + (j - 4)));
#pragma unroll
            for (int i = 0; i < 8; ++i) {
                float Cv  = __fmul_rn(2.0f, acc[i][j]);
                float t1v = __fadd_rn(a8[i], bvv[j]);
                float dv  = __fsub_rn(t1v, Cv);
                // strict < keeps first (lowest) index; c ascends per thread
                if (dv < v1[i]) { v1[i] = dv; i1[i] = c; }
            }
        }
    }

    // merge (val, idx) across the 16 col-group threads per row (via LDS)
    __syncthreads();
    float* Mv = sm;                        // [128][16] floats
    int*   Mi = (int*)(sm + 2048);         // [128][16] ints
#pragma unroll
    for (int i = 0; i < 8; ++i) {
        int r = ty * 8 + i;
        Mv[r * 16 + tx] = v1[i];
        Mi[r * 16 + tx] = i1[i];
    }
    __syncthreads();
    if (tid < TM) {
        int r = tid;
        float bv = Mv[r * 16];
        int   bi = Mi[r * 16];
        for (int t = 1; t < 16; ++t) {
            float av = Mv[r * 16 + t];
            int   ai = Mi[r * 16 + t];
            if (av < bv || (av == bv && ai < bi)) { bv = av; bi = ai; }
        }
        idx32[rowbase + r] = bi;
    }
#undef LOADR
#undef WRITE1
#undef WRITEB
}

// ---------------- K3: gather quantized + fp64 loss accumulation ------------
__global__ __launch_bounds__(256) void k_out(
    const float* __restrict__ X, const float* __restrict__ E,
    const int* __restrict__ idx32, float* __restrict__ out0,
    double* __restrict__ lossacc)
{
    const int NF4 = NQ / 4;
    double s = 0.0;
    for (int g = blockIdx.x * blockDim.x + threadIdx.x; g < NF4;
         g += gridDim.x * blockDim.x) {
        int row = g >> 6;
        int d4  = g & 63;
        int j = idx32[row];
        float4 q = *(const float4*)(E + (size_t)j * DIM + d4 * 4);
        float4 x = *(const float4*)(X + (size_t)g * 4);
        *(float4*)(out0 + (size_t)g * 4) = q;
        double dx;
        dx = (double)q.x - (double)x.x; s = fma(dx, dx, s);
        dx = (double)q.y - (double)x.y; s = fma(dx, dx, s);
        dx = (double)q.z - (double)x.z; s = fma(dx, dx, s);
        dx = (double)q.w - (double)x.w; s = fma(dx, dx, s);
    }
#pragma unroll
    for (int off = 32; off > 0; off >>= 1) s += __shfl_down(s, off, 64);
    __shared__ double wsum[4];
    int lane = threadIdx.x & 63, wv = threadIdx.x >> 6;
    if (lane == 0) wsum[wv] = s;
    __syncthreads();
    if (threadIdx.x == 0) {
        double t = wsum[0] + wsum[1] + wsum[2] + wsum[3];
        atomicAdd(lossacc, t);
    }
}

// ---------------- K3b: index output + histogram ----------------
__global__ __launch_bounds__(256) void k_idxout(
    const int* __restrict__ idx32, float* __restrict__ out1,
    int* __restrict__ counts)
{
    __shared__ int h[KC];
    for (int i = threadIdx.x; i < KC; i += 256) h[i] = 0;
    __syncthreads();
    int r = blockIdx.x * 256 + threadIdx.x;   // grid 256*256 = 65536 exact
    int j = idx32[r];
    out1[r] = (float)j;
    atomicAdd(&h[j], 1);
    __syncthreads();
    for (int i = threadIdx.x; i < KC; i += 256)
        if (h[i]) atomicAdd(&counts[i], h[i]);
}

// ---------------- K4: perplexity + loss finalize ----------------
__global__ void k_fin(const int* __restrict__ counts,
                      const double* __restrict__ lossacc,
                      float* __restrict__ out_pl)
{
    __shared__ double sh[256];
    double s = 0.0;
    for (int i = threadIdx.x; i < KC; i += 256) {
        double p = (double)counts[i] / 65536.0;
        s += p * log(p + 1.1920928955078125e-07);   // EPS = fp32 eps exactly
    }
    sh[threadIdx.x] = s;
    __syncthreads();
    for (int off = 128; off > 0; off >>= 1) {
        if (threadIdx.x < off) sh[threadIdx.x] += sh[threadIdx.x + off];
        __syncthreads();
    }
    if (threadIdx.x == 0) {
        out_pl[0] = (float)exp(-sh[0]);
        out_pl[1] = (float)((*lossacc / (double)NQ) * 1.1);  // q + 0.1*e latent
    }
}

extern "C" void kernel_launch(void* const* d_in, const int* in_sizes, int n_in,
                              void* d_out, int out_size, void* d_ws, size_t ws_size,
                              hipStream_t stream) {
    const float* X = (const float*)d_in[0];
    const float* E = (const float*)d_in[1];
    float* out = (float*)d_out;
    char* ws = (char*)d_ws;

    double* lossacc = (double*)(ws + 0);
    int*    counts  = (int*)(ws + 16);
    float*  B32     = (float*)(ws + 4224);
    int*    idx32   = (int*)(ws + 270464);

    // zero lossacc + counts (B32 fully overwritten by k_prepB)
    hipMemsetAsync(d_ws, 0, 4224, stream);

    hipLaunchKernelGGL(k_prepB, dim3(4),         dim3(256), 0, stream, E, B32);
    hipLaunchKernelGGL(k_pass1, dim3(ROWS / TM), dim3(256), 0, stream,
                       X, E, B32, idx32);
    hipLaunchKernelGGL(k_out,   dim3(2048),      dim3(256), 0, stream,
                       X, E, idx32, out, lossacc);
    hipLaunchKernelGGL(k_idxout, dim3(256),      dim3(256), 0, stream,
                       idx32, out + NQ, counts);
    hipLaunchKernelGGL(k_fin,   dim3(1),         dim3(256), 0, stream,
                       counts, lossacc, out + NQ + 65536);
}